// Round 7
// baseline (930.340 us; speedup 1.0000x reference)
//
#include <hip/hip_runtime.h>

constexpr int N_NODES = 40000;
constexpr int N_EDGES = 640000;

constexpr float C_INV8     = 0.125f;                  // 1/sqrt(64)
constexpr float C_INV_S32  = 0.17677669529663687f;    // 1/sqrt(32)
constexpr float C_INV_S3   = 0.57735026918962576f;    // 1/sqrt(3)
constexpr float C_INV_S2   = 0.70710678118654752f;    // 1/sqrt(2)
constexpr float C_INV_S96  = 0.10206207261596575f;    // 1/sqrt(96)
constexpr float C_INV_S128 = 0.08838834764831845f;    // 1/sqrt(128)
constexpr float C_INV_NN   = 0.25f;                   // 1/sqrt(16)

typedef __attribute__((ext_vector_type(8))) short short8;
typedef __attribute__((ext_vector_type(4))) float f32x4;

__device__ __forceinline__ unsigned short f2bf(float x) {
  __bf16 b = (__bf16)x;                      // hw v_cvt (RNE)
  return __builtin_bit_cast(unsigned short, b);
}
__device__ __forceinline__ float bf2f(unsigned short h) {
  return __uint_as_float(((unsigned int)h) << 16);
}

// ---- prep: bf16-transpose weights to [col][k]; fold agg scales into lin2 ----
__global__ __launch_bounds__(256) void k_prep(
    const float* __restrict__ fc_w1, const float* __restrict__ fc_w2,
    const float* __restrict__ lin2_ws, const float* __restrict__ lin2_wv,
    unsigned short* __restrict__ w1t, unsigned short* __restrict__ w2t,
    unsigned short* __restrict__ wst, unsigned short* __restrict__ wvt)
{
  int t = blockIdx.x * 256 + threadIdx.x;
  if (t < 4096) {                       // w1t: 64x64
    int c = t >> 6, k = t & 63;
    w1t[c * 64 + k] = f2bf(fc_w1[k * 64 + c]);
  } else if (t < 4096 + 14336) {        // w2t: 224x64
    int u = t - 4096; int c = u >> 6, k = u & 63;
    w2t[c * 64 + k] = f2bf(fc_w2[k * 224 + c]);
  } else if (t < 18432 + 9216) {        // wst: 96x96 (pre-scaled)
    int u = t - 18432; int c = u / 96, k = u - c * 96;
    wst[c * 96 + k] = f2bf(lin2_ws[k * 96 + c] * (C_INV_NN * C_INV_S96));
  } else if (t < 27648 + 4096) {        // wvt: 32x128 (pre-scaled)
    int u = t - 27648; int d = u >> 7, k = u & 127;
    wvt[d * 128 + k] = f2bf(lin2_wv[k * 32 + d] * (C_INV_NN * C_INV_S128));
  }
}

// ---------------- K1: fused h_s / h_v ----------------
__global__ __launch_bounds__(256) void k_node(
    const float* __restrict__ nf, const float* __restrict__ attr,
    const float* __restrict__ ws_, const float* __restrict__ wv_,
    float* __restrict__ h_s, float* __restrict__ h_v)
{
  int t = blockIdx.x * 256 + threadIdx.x;
  if (t < N_NODES * 64) {
    int n = t >> 6, c = t & 63;
    const float* s = nf + (long)n * 160;
    float acc = 0.f;
    #pragma unroll 8
    for (int k = 0; k < 64; ++k) acc = fmaf(s[k], ws_[k * 64 + c], acc);
    h_s[t] = acc * attr[n] * C_INV8;
  } else {
    int u = t - N_NODES * 64;
    if (u >= N_NODES * 32) return;
    int n = u >> 5, d = u & 31;
    const float* v = nf + (long)n * 160 + 64;
    float a0 = 0.f, a1 = 0.f, a2 = 0.f;
    #pragma unroll 8
    for (int c = 0; c < 32; ++c) {
      float wv = wv_[c * 32 + d];
      a0 = fmaf(v[3 * c + 0], wv, a0);
      a1 = fmaf(v[3 * c + 1], wv, a1);
      a2 = fmaf(v[3 * c + 2], wv, a2);
    }
    float sc = attr[n] * C_INV_S32;
    h_v[(long)u * 3 + 0] = a0 * sc;
    h_v[(long)u * 3 + 1] = a1 * sc;
    h_v[(long)u * 3 + 2] = a2 * sc;
  }
}

// ---------------- CSR build ----------------
__global__ __launch_bounds__(256) void k_deg(const int* __restrict__ edst,
                                             int* __restrict__ deg)
{
  int e = blockIdx.x * 256 + threadIdx.x;
  if (e < N_EDGES) atomicAdd(&deg[edst[e]], 1);
}

__global__ __launch_bounds__(1024) void k_scan(const int* __restrict__ deg,
                                               int* __restrict__ start,
                                               int* __restrict__ cursor)
{
  __shared__ int psum[1024];
  int tid = threadIdx.x;
  const int PER = 40;
  int base = tid * PER;
  int s = 0;
  for (int i = 0; i < PER; ++i) {
    int idx = base + i;
    if (idx < N_NODES) s += deg[idx];
  }
  psum[tid] = s;
  __syncthreads();
  for (int off = 1; off < 1024; off <<= 1) {
    int v = psum[tid];
    int u = (tid >= off) ? psum[tid - off] : 0;
    __syncthreads();
    psum[tid] = v + u;
    __syncthreads();
  }
  int run = (tid == 0) ? 0 : psum[tid - 1];
  for (int i = 0; i < PER; ++i) {
    int idx = base + i;
    if (idx < N_NODES) {
      start[idx] = run; cursor[idx] = run;
      run += deg[idx];
    }
  }
  if (tid == 1023) start[N_NODES] = run;
}

__global__ __launch_bounds__(256) void k_fill(const int* __restrict__ edst,
                                              int* __restrict__ cursor,
                                              int* __restrict__ eid)
{
  int e = blockIdx.x * 256 + threadIdx.x;
  if (e < N_EDGES) {
    int p = atomicAdd(&cursor[edst[e]], 1);
    eid[p] = e;
  }
}

// ---- K2: fused FC(MFMA) + messages + per-edge lin2(MFMA) -> sorted e_out ----
// block = 4 waves, 64 sorted-edge slots; wave w owns slots [16w,16w+16).
// ALL LDS warp-private -> ZERO barriers. hid staged inside own w_lds slice.
__global__ __launch_bounds__(256, 5) void k_edge2(
    const float* __restrict__ escal, const float* __restrict__ eattr,
    const int* __restrict__ esrc, const int* __restrict__ eid,
    const unsigned short* __restrict__ w1t, const unsigned short* __restrict__ w2t,
    const unsigned short* __restrict__ wst, const unsigned short* __restrict__ wvt,
    const float* __restrict__ h_s, const float* __restrict__ h_v,
    unsigned short* __restrict__ e_out)
{
  __shared__ unsigned short w_lds[64 * 232];    // 29.7 KB total (hid + w + o reuse)
  int tid = threadIdx.x, warp = tid >> 6, lane = tid & 63;
  int lr = lane & 15, lg = lane >> 4;
  long e0 = (long)blockIdx.x * 64;
  int r0 = warp * 16;
  unsigned short* wp = w_lds + r0 * 232;        // this warp's private 3712-short slice

  // ---- per-lane edge identity + ingredient prefetch (overlaps FC GEMMs) ----
  long pos = e0 + r0 + lr;                      // sorted slot
  int sid = eid[pos];                           // original edge id
  int srcM = esrc[sid];
  float4 ea4 = *reinterpret_cast<const float4*>(eattr + (long)sid * 4);
  float ea0 = ea4.x, e1x = ea4.y, e1y = ea4.z, e1z = ea4.w;
  float esv[16];
  {
    const float* hsr = h_s + (long)srcM * 64;
    *reinterpret_cast<float4*>(&esv[0])  = *reinterpret_cast<const float4*>(hsr + lg * 8);
    *reinterpret_cast<float4*>(&esv[4])  = *reinterpret_cast<const float4*>(hsr + lg * 8 + 4);
    *reinterpret_cast<float4*>(&esv[8])  = *reinterpret_cast<const float4*>(hsr + 32 + lg * 8);
    *reinterpret_cast<float4*>(&esv[12]) = *reinterpret_cast<const float4*>(hsr + 32 + lg * 8 + 4);
  }
  float evv[24];
  {
    const float* hvr = h_v + (long)srcM * 96 + lg * 24;
    #pragma unroll
    for (int q = 0; q < 6; ++q)
      *reinterpret_cast<float4*>(&evv[4 * q]) = *reinterpret_cast<const float4*>(hvr + 4 * q);
  }

  // ---- layer1: hid = silu((escal @ W1)/8); A rows gathered via eid ----
  f32x4 acc[4] = {};
  #pragma unroll
  for (int ks = 0; ks < 2; ++ks) {
    const float* ap = escal + (long)sid * 64 + ks * 32 + lg * 8;
    float4 a01 = *reinterpret_cast<const float4*>(ap);
    float4 a23 = *reinterpret_cast<const float4*>(ap + 4);
    short8 af;
    af[0] = (short)f2bf(a01.x); af[1] = (short)f2bf(a01.y);
    af[2] = (short)f2bf(a01.z); af[3] = (short)f2bf(a01.w);
    af[4] = (short)f2bf(a23.x); af[5] = (short)f2bf(a23.y);
    af[6] = (short)f2bf(a23.z); af[7] = (short)f2bf(a23.w);
    #pragma unroll
    for (int nt = 0; nt < 4; ++nt) {
      short8 bf = *reinterpret_cast<const short8*>(w1t + (nt * 16 + lr) * 64 + ks * 32 + lg * 8);
      acc[nt] = __builtin_amdgcn_mfma_f32_16x16x32_bf16(af, bf, acc[nt], 0, 0, 0);
    }
  }
  // hid staged at stride 72 inside own warp slice (rows local 0..15)
  #pragma unroll
  for (int nt = 0; nt < 4; ++nt)
    #pragma unroll
    for (int r = 0; r < 4; ++r) {
      float x = acc[nt][r] * C_INV8;
      float h = x / (1.f + __expf(-x));
      wp[(lg * 4 + r) * 72 + nt * 16 + lr] = f2bf(h);
    }

  // ---- layer2: w = (hid @ W2)/8 ----
  f32x4 acc2[14] = {};
  #pragma unroll
  for (int ks = 0; ks < 2; ++ks) {
    short8 af = *reinterpret_cast<const short8*>(wp + lr * 72 + ks * 32 + lg * 8);
    #pragma unroll
    for (int nt = 0; nt < 14; ++nt) {
      short8 bf = *reinterpret_cast<const short8*>(w2t + (nt * 16 + lr) * 64 + ks * 32 + lg * 8);
      acc2[nt] = __builtin_amdgcn_mfma_f32_16x16x32_bf16(af, bf, acc2[nt], 0, 0, 0);
    }
  }
  // w overwrites the slice at stride 232 (after all hid reads; in-wave order)
  #pragma unroll
  for (int nt = 0; nt < 14; ++nt)
    #pragma unroll
    for (int r = 0; r < 4; ++r)
      wp[(lg * 4 + r) * 232 + nt * 16 + lr] = f2bf(acc2[nt][r] * C_INV8);

  const unsigned short* wrow = wp + lr * 232;
  short8 w1a = *reinterpret_cast<const short8*>(wrow + lg * 8);
  short8 w1b = *reinterpret_cast<const short8*>(wrow + 32 + lg * 8);
  short8 w2a = *reinterpret_cast<const short8*>(wrow + 64 + lg * 8);
  short8 w2b = *reinterpret_cast<const short8*>(wrow + 96 + lg * 8);
  short8 w3s = *reinterpret_cast<const short8*>(wrow + 128 + lg * 8);
  short8 w4s = *reinterpret_cast<const short8*>(wrow + 160 + lg * 8);
  short8 w5s = *reinterpret_cast<const short8*>(wrow + 192 + lg * 8);

  // ---- S-GEMM: [16 edges x 96 mid_s] @ wst -> 16x96 (scaled) ----
  f32x4 accS[6] = {};
  {
    short8 aS;
    #pragma unroll
    for (int j = 0; j < 8; ++j) aS[j] = (short)f2bf(bf2f((unsigned short)w1a[j]) * esv[j] * ea0);
    #pragma unroll
    for (int nt = 0; nt < 6; ++nt) {
      short8 b = *reinterpret_cast<const short8*>(wst + (nt * 16 + lr) * 96 + lg * 8);
      accS[nt] = __builtin_amdgcn_mfma_f32_16x16x32_bf16(aS, b, accS[nt], 0, 0, 0);
    }
    #pragma unroll
    for (int j = 0; j < 8; ++j) aS[j] = (short)f2bf(bf2f((unsigned short)w1b[j]) * esv[8 + j] * ea0);
    #pragma unroll
    for (int nt = 0; nt < 6; ++nt) {
      short8 b = *reinterpret_cast<const short8*>(wst + (nt * 16 + lr) * 96 + 32 + lg * 8);
      accS[nt] = __builtin_amdgcn_mfma_f32_16x16x32_bf16(aS, b, accS[nt], 0, 0, 0);
    }
    #pragma unroll
    for (int j = 0; j < 8; ++j) {
      float dot = evv[3 * j] * e1x + evv[3 * j + 1] * e1y + evv[3 * j + 2] * e1z;
      aS[j] = (short)f2bf(bf2f((unsigned short)w4s[j]) * dot * C_INV_S3);
    }
    #pragma unroll
    for (int nt = 0; nt < 6; ++nt) {
      short8 b = *reinterpret_cast<const short8*>(wst + (nt * 16 + lr) * 96 + 64 + lg * 8);
      accS[nt] = __builtin_amdgcn_mfma_f32_16x16x32_bf16(aS, b, accS[nt], 0, 0, 0);
    }
  }

  // ---- V-GEMMs: per comp i, [16 x 128 mid_v_i] @ wvt -> 16x32 (scaled) ----
  f32x4 accV[6] = {};
  #pragma unroll
  for (int i = 0; i < 3; ++i) {
    float e1i = (i == 0) ? e1x : (i == 1) ? e1y : e1z;
    short8 aV;
    #pragma unroll
    for (int j = 0; j < 8; ++j) aV[j] = (short)f2bf(bf2f((unsigned short)w2a[j]) * esv[j] * e1i);
    #pragma unroll
    for (int nt = 0; nt < 2; ++nt) {
      short8 b = *reinterpret_cast<const short8*>(wvt + (nt * 16 + lr) * 128 + lg * 8);
      accV[i * 2 + nt] = __builtin_amdgcn_mfma_f32_16x16x32_bf16(aV, b, accV[i * 2 + nt], 0, 0, 0);
    }
    #pragma unroll
    for (int j = 0; j < 8; ++j) aV[j] = (short)f2bf(bf2f((unsigned short)w2b[j]) * esv[8 + j] * e1i);
    #pragma unroll
    for (int nt = 0; nt < 2; ++nt) {
      short8 b = *reinterpret_cast<const short8*>(wvt + (nt * 16 + lr) * 128 + 32 + lg * 8);
      accV[i * 2 + nt] = __builtin_amdgcn_mfma_f32_16x16x32_bf16(aV, b, accV[i * 2 + nt], 0, 0, 0);
    }
    #pragma unroll
    for (int j = 0; j < 8; ++j) aV[j] = (short)f2bf(bf2f((unsigned short)w3s[j]) * evv[3 * j + i] * ea0);
    #pragma unroll
    for (int nt = 0; nt < 2; ++nt) {
      short8 b = *reinterpret_cast<const short8*>(wvt + (nt * 16 + lr) * 128 + 64 + lg * 8);
      accV[i * 2 + nt] = __builtin_amdgcn_mfma_f32_16x16x32_bf16(aV, b, accV[i * 2 + nt], 0, 0, 0);
    }
    #pragma unroll
    for (int j = 0; j < 8; ++j) {
      float ex = evv[3 * j], ey = evv[3 * j + 1], ez = evv[3 * j + 2];
      float cr = (i == 0) ? (ey * e1z - ez * e1y)
               : (i == 1) ? (ez * e1x - ex * e1z)
                          : (ex * e1y - ey * e1x);
      aV[j] = (short)f2bf(bf2f((unsigned short)w5s[j]) * cr * C_INV_S2);
    }
    #pragma unroll
    for (int nt = 0; nt < 2; ++nt) {
      short8 b = *reinterpret_cast<const short8*>(wvt + (nt * 16 + lr) * 128 + 96 + lg * 8);
      accV[i * 2 + nt] = __builtin_amdgcn_mfma_f32_16x16x32_bf16(aV, b, accV[i * 2 + nt], 0, 0, 0);
    }
  }

  // ---- stage o (192 bf16/edge) into own warp slice (stride 232) ----
  #pragma unroll
  for (int nt = 0; nt < 6; ++nt)
    #pragma unroll
    for (int r = 0; r < 4; ++r)
      wp[(lg * 4 + r) * 232 + nt * 16 + lr] = f2bf(accS[nt][r]);
  #pragma unroll
  for (int q = 0; q < 6; ++q) {
    int i = q >> 1, nt = q & 1;
    #pragma unroll
    for (int r = 0; r < 4; ++r)
      wp[(lg * 4 + r) * 232 + 96 + i * 32 + nt * 16 + lr] = f2bf(accV[q][r]);
  }

  // ---- per-warp coalesced store to SORTED rows ----
  #pragma unroll
  for (int c3 = 0; c3 < 6; ++c3) {
    int chunk = c3 * 64 + lane;           // 0..383
    int row = chunk / 24, col = chunk % 24;
    float4 v4 = *reinterpret_cast<const float4*>(wp + row * 232 + col * 8);
    *reinterpret_cast<float4*>(e_out + (e0 + r0 + row) * 192 + col * 8) = v4;
  }
}

// ---- K_agg: sequential streaming reduce (e_out is dst-sorted) ----
__global__ __launch_bounds__(256) void k_agg(
    const int* __restrict__ start, const unsigned short* __restrict__ eo,
    float* __restrict__ agg)
{
  int t = blockIdx.x * 256 + threadIdx.x;
  if (t >= N_NODES * 96) return;
  int n = t / 96, c = t - n * 96;
  int s0 = start[n], s1 = start[n + 1];
  const unsigned int* base = reinterpret_cast<const unsigned int*>(eo);
  float a0 = 0.f, a1 = 0.f;
  long idx = (long)s0 * 96 + c;
  int k = s0;
  for (; k + 8 <= s1; k += 8) {
    unsigned int v[8];
    #pragma unroll
    for (int j = 0; j < 8; ++j) v[j] = base[idx + (long)j * 96];
    #pragma unroll
    for (int j = 0; j < 8; ++j) {
      a0 += bf2f((unsigned short)(v[j] & 0xffffu));
      a1 += bf2f((unsigned short)(v[j] >> 16));
    }
    idx += 8 * 96;
  }
  for (; k < s1; ++k) {
    unsigned int v = base[idx];
    a0 += bf2f((unsigned short)(v & 0xffffu));
    a1 += bf2f((unsigned short)(v >> 16));
    idx += 96;
  }
  agg[(long)n * 192 + 2 * c]     = a0;
  agg[(long)n * 192 + 2 * c + 1] = a1;
}

// ---------------- K3: fused output head ----------------
__global__ __launch_bounds__(256) void k_fin(
    const float* __restrict__ nf, const float* __restrict__ attr,
    const float* __restrict__ agg, const float* __restrict__ sc_ws,
    const float* __restrict__ sc_wv, float* __restrict__ out)
{
  int t = blockIdx.x * 256 + threadIdx.x;
  if (t < N_NODES * 64) {              // scalar outputs
    int n = t >> 6, cch = t & 63;
    const float* s = nf + (long)n * 160;
    float acc2 = 0.f;
    #pragma unroll 8
    for (int k = 0; k < 64; ++k) acc2 = fmaf(s[k], sc_ws[k * 96 + cch], acc2);
    float pre = (agg[(long)n * 192 + cch] + acc2 * C_INV8) * attr[n];
    out[(long)n * 160 + cch] = pre / (1.f + __expf(-pre));
  } else {                             // vector outputs (gate recomputed)
    int u = t - N_NODES * 64;
    if (u >= N_NODES * 32) return;
    int n = u >> 5, d = u & 31;
    const float* s = nf + (long)n * 160;
    float a = attr[n];
    float gacc = 0.f;
    #pragma unroll 8
    for (int k = 0; k < 64; ++k) gacc = fmaf(s[k], sc_ws[k * 96 + 64 + d], gacc);
    float gpre = (agg[(long)n * 192 + 64 + d] + gacc * C_INV8) * a;
    float g = 1.f / (1.f + __expf(-gpre));
    const float* v = s + 64;
    float s0 = 0.f, s1 = 0.f, s2 = 0.f;
    #pragma unroll 8
    for (int cc = 0; cc < 32; ++cc) {
      float wv = sc_wv[cc * 32 + d];
      s0 = fmaf(v[3 * cc + 0], wv, s0);
      s1 = fmaf(v[3 * cc + 1], wv, s1);
      s2 = fmaf(v[3 * cc + 2], wv, s2);
    }
    const float* ag = agg + (long)n * 192 + 96;
    float p0 = (ag[d]      + s0 * C_INV_S32) * a;
    float p1 = (ag[32 + d] + s1 * C_INV_S32) * a;
    float p2 = (ag[64 + d] + s2 * C_INV_S32) * a;
    float* o = out + (long)n * 160 + 64 + 3 * d;
    o[0] = g * p0; o[1] = g * p1; o[2] = g * p2;
  }
}

extern "C" void kernel_launch(void* const* d_in, const int* in_sizes, int n_in,
                              void* d_out, int out_size, void* d_ws, size_t ws_size,
                              hipStream_t stream)
{
  const float* nf      = (const float*)d_in[0];
  const float* attr    = (const float*)d_in[1];
  const int*   esrc    = (const int*)d_in[2];
  const int*   edst    = (const int*)d_in[3];
  const float* eattr   = (const float*)d_in[4];
  const float* escal   = (const float*)d_in[5];
  const float* lin1_ws = (const float*)d_in[6];
  const float* lin1_wv = (const float*)d_in[7];
  const float* fc_w1   = (const float*)d_in[8];
  const float* fc_w2   = (const float*)d_in[9];
  const float* sc_ws   = (const float*)d_in[10];
  const float* sc_wv   = (const float*)d_in[11];
  const float* lin2_ws = (const float*)d_in[12];
  const float* lin2_wv = (const float*)d_in[13];
  float* out = (float*)d_out;

  char* base = (char*)d_ws;
  size_t off = 0;
  auto carve = [&](size_t bytes) { void* p = base + off; off = (off + bytes + 63) & ~(size_t)63; return p; };
  float* h_s   = (float*)carve((size_t)N_NODES * 64 * 4);
  float* h_v   = (float*)carve((size_t)N_NODES * 96 * 4);
  float* agg   = (float*)carve((size_t)N_NODES * 192 * 4);
  unsigned short* w1t = (unsigned short*)carve(4096 * 2);
  unsigned short* w2t = (unsigned short*)carve(14336 * 2);
  unsigned short* wst = (unsigned short*)carve(9216 * 2);
  unsigned short* wvt = (unsigned short*)carve(4096 * 2);
  int* deg    = (int*)carve((size_t)N_NODES * 4);
  int* startp = (int*)carve((size_t)(N_NODES + 1) * 4);
  int* cursor = (int*)carve((size_t)N_NODES * 4);
  int* eid    = (int*)carve((size_t)N_EDGES * 4);
  unsigned short* e_out = (unsigned short*)carve((size_t)N_EDGES * 192 * 2);

  k_prep<<<124, 256, 0, stream>>>(fc_w1, fc_w2, lin2_ws, lin2_wv, w1t, w2t, wst, wvt);
  k_node<<<(N_NODES * 96 + 255) / 256, 256, 0, stream>>>(nf, attr, lin1_ws, lin1_wv, h_s, h_v);

  hipMemsetAsync(deg, 0, (size_t)N_NODES * 4, stream);
  k_deg<<<(N_EDGES + 255) / 256, 256, 0, stream>>>(edst, deg);
  k_scan<<<1, 1024, 0, stream>>>(deg, startp, cursor);
  k_fill<<<(N_EDGES + 255) / 256, 256, 0, stream>>>(edst, cursor, eid);
  k_edge2<<<N_EDGES / 64, 256, 0, stream>>>(escal, eattr, esrc, eid,
                                            w1t, w2t, wst, wvt, h_s, h_v, e_out);
  k_agg<<<(N_NODES * 96 + 255) / 256, 256, 0, stream>>>(startp, e_out, agg);
  k_fin<<<(N_NODES * 96 + 255) / 256, 256, 0, stream>>>(nf, attr, agg, sc_ws, sc_wv, out);
}

// Round 8
// 890.495 us; speedup vs baseline: 1.0447x; 1.0447x over previous
//
#include <hip/hip_runtime.h>

constexpr int N_NODES = 40000;
constexpr int N_EDGES = 640000;

constexpr float C_INV8     = 0.125f;                  // 1/sqrt(64)
constexpr float C_INV_S32  = 0.17677669529663687f;    // 1/sqrt(32)
constexpr float C_INV_S3   = 0.57735026918962576f;    // 1/sqrt(3)
constexpr float C_INV_S2   = 0.70710678118654752f;    // 1/sqrt(2)
constexpr float C_INV_S96  = 0.10206207261596575f;    // 1/sqrt(96)
constexpr float C_INV_S128 = 0.08838834764831845f;    // 1/sqrt(128)
constexpr float C_INV_NN   = 0.25f;                   // 1/sqrt(16)

typedef __attribute__((ext_vector_type(8))) short short8;
typedef __attribute__((ext_vector_type(4))) float f32x4;

__device__ __forceinline__ unsigned short f2bf(float x) {
  __bf16 b = (__bf16)x;                      // hw v_cvt (RNE)
  return __builtin_bit_cast(unsigned short, b);
}
__device__ __forceinline__ float bf2f(unsigned short h) {
  return __uint_as_float(((unsigned int)h) << 16);
}

// ---- prep: bf16-transpose weights to [col][k]; fold agg scales into lin2 ----
__global__ __launch_bounds__(256) void k_prep(
    const float* __restrict__ fc_w1, const float* __restrict__ fc_w2,
    const float* __restrict__ lin2_ws, const float* __restrict__ lin2_wv,
    unsigned short* __restrict__ w1t, unsigned short* __restrict__ w2t,
    unsigned short* __restrict__ wst, unsigned short* __restrict__ wvt)
{
  int t = blockIdx.x * 256 + threadIdx.x;
  if (t < 4096) {                       // w1t: 64x64
    int c = t >> 6, k = t & 63;
    w1t[c * 64 + k] = f2bf(fc_w1[k * 64 + c]);
  } else if (t < 4096 + 14336) {        // w2t: 224x64
    int u = t - 4096; int c = u >> 6, k = u & 63;
    w2t[c * 64 + k] = f2bf(fc_w2[k * 224 + c]);
  } else if (t < 18432 + 9216) {        // wst: 96x96 (pre-scaled)
    int u = t - 18432; int c = u / 96, k = u - c * 96;
    wst[c * 96 + k] = f2bf(lin2_ws[k * 96 + c] * (C_INV_NN * C_INV_S96));
  } else if (t < 27648 + 4096) {        // wvt: 32x128 (pre-scaled)
    int u = t - 27648; int d = u >> 7, k = u & 127;
    wvt[d * 128 + k] = f2bf(lin2_wv[k * 32 + d] * (C_INV_NN * C_INV_S128));
  }
}

// ---------------- K1: fused h_s / h_v ----------------
__global__ __launch_bounds__(256) void k_node(
    const float* __restrict__ nf, const float* __restrict__ attr,
    const float* __restrict__ ws_, const float* __restrict__ wv_,
    float* __restrict__ h_s, float* __restrict__ h_v)
{
  int t = blockIdx.x * 256 + threadIdx.x;
  if (t < N_NODES * 64) {
    int n = t >> 6, c = t & 63;
    const float* s = nf + (long)n * 160;
    float acc = 0.f;
    #pragma unroll 8
    for (int k = 0; k < 64; ++k) acc = fmaf(s[k], ws_[k * 64 + c], acc);
    h_s[t] = acc * attr[n] * C_INV8;
  } else {
    int u = t - N_NODES * 64;
    if (u >= N_NODES * 32) return;
    int n = u >> 5, d = u & 31;
    const float* v = nf + (long)n * 160 + 64;
    float a0 = 0.f, a1 = 0.f, a2 = 0.f;
    #pragma unroll 8
    for (int c = 0; c < 32; ++c) {
      float wv = wv_[c * 32 + d];
      a0 = fmaf(v[3 * c + 0], wv, a0);
      a1 = fmaf(v[3 * c + 1], wv, a1);
      a2 = fmaf(v[3 * c + 2], wv, a2);
    }
    float sc = attr[n] * C_INV_S32;
    h_v[(long)u * 3 + 0] = a0 * sc;
    h_v[(long)u * 3 + 1] = a1 * sc;
    h_v[(long)u * 3 + 2] = a2 * sc;
  }
}

// ---------------- CSR build ----------------
__global__ __launch_bounds__(256) void k_deg(const int* __restrict__ edst,
                                             int* __restrict__ deg)
{
  int e = blockIdx.x * 256 + threadIdx.x;
  if (e < N_EDGES) atomicAdd(&deg[edst[e]], 1);
}

__global__ __launch_bounds__(1024) void k_scan(const int* __restrict__ deg,
                                               int* __restrict__ start,
                                               int* __restrict__ cursor)
{
  __shared__ int psum[1024];
  int tid = threadIdx.x;
  const int PER = 40;
  int base = tid * PER;
  int s = 0;
  for (int i = 0; i < PER; ++i) {
    int idx = base + i;
    if (idx < N_NODES) s += deg[idx];
  }
  psum[tid] = s;
  __syncthreads();
  for (int off = 1; off < 1024; off <<= 1) {
    int v = psum[tid];
    int u = (tid >= off) ? psum[tid - off] : 0;
    __syncthreads();
    psum[tid] = v + u;
    __syncthreads();
  }
  int run = (tid == 0) ? 0 : psum[tid - 1];
  for (int i = 0; i < PER; ++i) {
    int idx = base + i;
    if (idx < N_NODES) {
      start[idx] = run; cursor[idx] = run;
      run += deg[idx];
    }
  }
  if (tid == 1023) start[N_NODES] = run;
}

// pos[e] = sorted slot of edge e (inverse permutation)
__global__ __launch_bounds__(256) void k_fill(const int* __restrict__ edst,
                                              int* __restrict__ cursor,
                                              int* __restrict__ pos)
{
  int e = blockIdx.x * 256 + threadIdx.x;
  if (e < N_EDGES) {
    int p = atomicAdd(&cursor[edst[e]], 1);
    pos[e] = p;
  }
}

// ---- K2: fused FC(MFMA) + messages + per-edge lin2(MFMA) -> scatter e_out ----
// Edges processed in ORIGINAL order (sequential reads); rows scatter-stored to
// dst-sorted slots pos[e]. block = 4 waves x 16 edges; LDS warp-private, 0 barriers.
__global__ __launch_bounds__(256, 5) void k_edge2(
    const float* __restrict__ escal, const float* __restrict__ eattr,
    const int* __restrict__ esrc, const int* __restrict__ pos,
    const unsigned short* __restrict__ w1t, const unsigned short* __restrict__ w2t,
    const unsigned short* __restrict__ wst, const unsigned short* __restrict__ wvt,
    const float* __restrict__ h_s, const float* __restrict__ h_v,
    unsigned short* __restrict__ e_out)
{
  __shared__ unsigned short w_lds[64 * 232];    // 29.7 KB (hid + w + o reuse)
  int tid = threadIdx.x, warp = tid >> 6, lane = tid & 63;
  int lr = lane & 15, lg = lane >> 4;
  long e0 = (long)blockIdx.x * 64;
  int r0 = warp * 16;
  unsigned short* wp = w_lds + r0 * 232;        // warp-private slice

  // ---- per-lane edge ingredients (sequential edge id) ----
  long eM = e0 + r0 + lr;
  int srcM = esrc[eM];
  float4 ea4 = *reinterpret_cast<const float4*>(eattr + eM * 4);
  float ea0 = ea4.x, e1x = ea4.y, e1y = ea4.z, e1z = ea4.w;
  float esv[16];
  {
    const float* hsr = h_s + (long)srcM * 64;
    *reinterpret_cast<float4*>(&esv[0])  = *reinterpret_cast<const float4*>(hsr + lg * 8);
    *reinterpret_cast<float4*>(&esv[4])  = *reinterpret_cast<const float4*>(hsr + lg * 8 + 4);
    *reinterpret_cast<float4*>(&esv[8])  = *reinterpret_cast<const float4*>(hsr + 32 + lg * 8);
    *reinterpret_cast<float4*>(&esv[12]) = *reinterpret_cast<const float4*>(hsr + 32 + lg * 8 + 4);
  }
  float evv[24];
  {
    const float* hvr = h_v + (long)srcM * 96 + lg * 24;
    #pragma unroll
    for (int q = 0; q < 6; ++q)
      *reinterpret_cast<float4*>(&evv[4 * q]) = *reinterpret_cast<const float4*>(hvr + 4 * q);
  }

  // ---- layer1: hid = silu((escal @ W1)/8); sequential A rows ----
  f32x4 acc[4] = {};
  #pragma unroll
  for (int ks = 0; ks < 2; ++ks) {
    const float* ap = escal + eM * 64 + ks * 32 + lg * 8;
    float4 a01 = *reinterpret_cast<const float4*>(ap);
    float4 a23 = *reinterpret_cast<const float4*>(ap + 4);
    short8 af;
    af[0] = (short)f2bf(a01.x); af[1] = (short)f2bf(a01.y);
    af[2] = (short)f2bf(a01.z); af[3] = (short)f2bf(a01.w);
    af[4] = (short)f2bf(a23.x); af[5] = (short)f2bf(a23.y);
    af[6] = (short)f2bf(a23.z); af[7] = (short)f2bf(a23.w);
    #pragma unroll
    for (int nt = 0; nt < 4; ++nt) {
      short8 bf = *reinterpret_cast<const short8*>(w1t + (nt * 16 + lr) * 64 + ks * 32 + lg * 8);
      acc[nt] = __builtin_amdgcn_mfma_f32_16x16x32_bf16(af, bf, acc[nt], 0, 0, 0);
    }
  }
  #pragma unroll
  for (int nt = 0; nt < 4; ++nt)
    #pragma unroll
    for (int r = 0; r < 4; ++r) {
      float x = acc[nt][r] * C_INV8;
      float h = x / (1.f + __expf(-x));
      wp[(lg * 4 + r) * 72 + nt * 16 + lr] = f2bf(h);
    }

  // ---- layer2: w = (hid @ W2)/8 ----
  f32x4 acc2[14] = {};
  #pragma unroll
  for (int ks = 0; ks < 2; ++ks) {
    short8 af = *reinterpret_cast<const short8*>(wp + lr * 72 + ks * 32 + lg * 8);
    #pragma unroll
    for (int nt = 0; nt < 14; ++nt) {
      short8 bf = *reinterpret_cast<const short8*>(w2t + (nt * 16 + lr) * 64 + ks * 32 + lg * 8);
      acc2[nt] = __builtin_amdgcn_mfma_f32_16x16x32_bf16(af, bf, acc2[nt], 0, 0, 0);
    }
  }
  #pragma unroll
  for (int nt = 0; nt < 14; ++nt)
    #pragma unroll
    for (int r = 0; r < 4; ++r)
      wp[(lg * 4 + r) * 232 + nt * 16 + lr] = f2bf(acc2[nt][r] * C_INV8);

  const unsigned short* wrow = wp + lr * 232;
  short8 w1a = *reinterpret_cast<const short8*>(wrow + lg * 8);
  short8 w1b = *reinterpret_cast<const short8*>(wrow + 32 + lg * 8);
  short8 w2a = *reinterpret_cast<const short8*>(wrow + 64 + lg * 8);
  short8 w2b = *reinterpret_cast<const short8*>(wrow + 96 + lg * 8);
  short8 w3s = *reinterpret_cast<const short8*>(wrow + 128 + lg * 8);
  short8 w4s = *reinterpret_cast<const short8*>(wrow + 160 + lg * 8);
  short8 w5s = *reinterpret_cast<const short8*>(wrow + 192 + lg * 8);

  // ---- S-GEMM: [16 edges x 96 mid_s] @ wst -> 16x96 (scaled) ----
  f32x4 accS[6] = {};
  {
    short8 aS;
    #pragma unroll
    for (int j = 0; j < 8; ++j) aS[j] = (short)f2bf(bf2f((unsigned short)w1a[j]) * esv[j] * ea0);
    #pragma unroll
    for (int nt = 0; nt < 6; ++nt) {
      short8 b = *reinterpret_cast<const short8*>(wst + (nt * 16 + lr) * 96 + lg * 8);
      accS[nt] = __builtin_amdgcn_mfma_f32_16x16x32_bf16(aS, b, accS[nt], 0, 0, 0);
    }
    #pragma unroll
    for (int j = 0; j < 8; ++j) aS[j] = (short)f2bf(bf2f((unsigned short)w1b[j]) * esv[8 + j] * ea0);
    #pragma unroll
    for (int nt = 0; nt < 6; ++nt) {
      short8 b = *reinterpret_cast<const short8*>(wst + (nt * 16 + lr) * 96 + 32 + lg * 8);
      accS[nt] = __builtin_amdgcn_mfma_f32_16x16x32_bf16(aS, b, accS[nt], 0, 0, 0);
    }
    #pragma unroll
    for (int j = 0; j < 8; ++j) {
      float dot = evv[3 * j] * e1x + evv[3 * j + 1] * e1y + evv[3 * j + 2] * e1z;
      aS[j] = (short)f2bf(bf2f((unsigned short)w4s[j]) * dot * C_INV_S3);
    }
    #pragma unroll
    for (int nt = 0; nt < 6; ++nt) {
      short8 b = *reinterpret_cast<const short8*>(wst + (nt * 16 + lr) * 96 + 64 + lg * 8);
      accS[nt] = __builtin_amdgcn_mfma_f32_16x16x32_bf16(aS, b, accS[nt], 0, 0, 0);
    }
  }

  // ---- V-GEMMs: per comp i, [16 x 128 mid_v_i] @ wvt -> 16x32 (scaled) ----
  f32x4 accV[6] = {};
  #pragma unroll
  for (int i = 0; i < 3; ++i) {
    float e1i = (i == 0) ? e1x : (i == 1) ? e1y : e1z;
    short8 aV;
    #pragma unroll
    for (int j = 0; j < 8; ++j) aV[j] = (short)f2bf(bf2f((unsigned short)w2a[j]) * esv[j] * e1i);
    #pragma unroll
    for (int nt = 0; nt < 2; ++nt) {
      short8 b = *reinterpret_cast<const short8*>(wvt + (nt * 16 + lr) * 128 + lg * 8);
      accV[i * 2 + nt] = __builtin_amdgcn_mfma_f32_16x16x32_bf16(aV, b, accV[i * 2 + nt], 0, 0, 0);
    }
    #pragma unroll
    for (int j = 0; j < 8; ++j) aV[j] = (short)f2bf(bf2f((unsigned short)w2b[j]) * esv[8 + j] * e1i);
    #pragma unroll
    for (int nt = 0; nt < 2; ++nt) {
      short8 b = *reinterpret_cast<const short8*>(wvt + (nt * 16 + lr) * 128 + 32 + lg * 8);
      accV[i * 2 + nt] = __builtin_amdgcn_mfma_f32_16x16x32_bf16(aV, b, accV[i * 2 + nt], 0, 0, 0);
    }
    #pragma unroll
    for (int j = 0; j < 8; ++j) aV[j] = (short)f2bf(bf2f((unsigned short)w3s[j]) * evv[3 * j + i] * ea0);
    #pragma unroll
    for (int nt = 0; nt < 2; ++nt) {
      short8 b = *reinterpret_cast<const short8*>(wvt + (nt * 16 + lr) * 128 + 64 + lg * 8);
      accV[i * 2 + nt] = __builtin_amdgcn_mfma_f32_16x16x32_bf16(aV, b, accV[i * 2 + nt], 0, 0, 0);
    }
    #pragma unroll
    for (int j = 0; j < 8; ++j) {
      float ex = evv[3 * j], ey = evv[3 * j + 1], ez = evv[3 * j + 2];
      float cr = (i == 0) ? (ey * e1z - ez * e1y)
               : (i == 1) ? (ez * e1x - ex * e1z)
                          : (ex * e1y - ey * e1x);
      aV[j] = (short)f2bf(bf2f((unsigned short)w5s[j]) * cr * C_INV_S2);
    }
    #pragma unroll
    for (int nt = 0; nt < 2; ++nt) {
      short8 b = *reinterpret_cast<const short8*>(wvt + (nt * 16 + lr) * 128 + 96 + lg * 8);
      accV[i * 2 + nt] = __builtin_amdgcn_mfma_f32_16x16x32_bf16(aV, b, accV[i * 2 + nt], 0, 0, 0);
    }
  }

  // ---- stage o (192 bf16/edge) into own warp slice (stride 232) ----
  #pragma unroll
  for (int nt = 0; nt < 6; ++nt)
    #pragma unroll
    for (int r = 0; r < 4; ++r)
      wp[(lg * 4 + r) * 232 + nt * 16 + lr] = f2bf(accS[nt][r]);
  #pragma unroll
  for (int q = 0; q < 6; ++q) {
    int i = q >> 1, nt = q & 1;
    #pragma unroll
    for (int r = 0; r < 4; ++r)
      wp[(lg * 4 + r) * 232 + 96 + i * 32 + nt * 16 + lr] = f2bf(accV[q][r]);
  }

  // ---- scatter-store: row -> sorted slot pos[e] (writes are fire-and-forget) ----
  #pragma unroll
  for (int c3 = 0; c3 < 6; ++c3) {
    int chunk = c3 * 64 + lane;           // 0..383
    int row = chunk / 24, col = chunk % 24;
    int p = pos[e0 + r0 + row];           // L1-hit after first touch
    float4 v4 = *reinterpret_cast<const float4*>(wp + row * 232 + col * 8);
    *reinterpret_cast<float4*>(e_out + (long)p * 192 + col * 8) = v4;
  }
}

// ---- K_agg: sequential streaming reduce (e_out is dst-sorted) ----
__global__ __launch_bounds__(256) void k_agg(
    const int* __restrict__ start, const unsigned short* __restrict__ eo,
    float* __restrict__ agg)
{
  int t = blockIdx.x * 256 + threadIdx.x;
  if (t >= N_NODES * 96) return;
  int n = t / 96, c = t - n * 96;
  int s0 = start[n], s1 = start[n + 1];
  const unsigned int* base = reinterpret_cast<const unsigned int*>(eo);
  float a0 = 0.f, a1 = 0.f;
  long idx = (long)s0 * 96 + c;
  int k = s0;
  for (; k + 8 <= s1; k += 8) {
    unsigned int v[8];
    #pragma unroll
    for (int j = 0; j < 8; ++j) v[j] = base[idx + (long)j * 96];
    #pragma unroll
    for (int j = 0; j < 8; ++j) {
      a0 += bf2f((unsigned short)(v[j] & 0xffffu));
      a1 += bf2f((unsigned short)(v[j] >> 16));
    }
    idx += 8 * 96;
  }
  for (; k < s1; ++k) {
    unsigned int v = base[idx];
    a0 += bf2f((unsigned short)(v & 0xffffu));
    a1 += bf2f((unsigned short)(v >> 16));
    idx += 96;
  }
  agg[(long)n * 192 + 2 * c]     = a0;
  agg[(long)n * 192 + 2 * c + 1] = a1;
}

// ---------------- K3: fused output head ----------------
__global__ __launch_bounds__(256) void k_fin(
    const float* __restrict__ nf, const float* __restrict__ attr,
    const float* __restrict__ agg, const float* __restrict__ sc_ws,
    const float* __restrict__ sc_wv, float* __restrict__ out)
{
  int t = blockIdx.x * 256 + threadIdx.x;
  if (t < N_NODES * 64) {              // scalar outputs
    int n = t >> 6, cch = t & 63;
    const float* s = nf + (long)n * 160;
    float acc2 = 0.f;
    #pragma unroll 8
    for (int k = 0; k < 64; ++k) acc2 = fmaf(s[k], sc_ws[k * 96 + cch], acc2);
    float pre = (agg[(long)n * 192 + cch] + acc2 * C_INV8) * attr[n];
    out[(long)n * 160 + cch] = pre / (1.f + __expf(-pre));
  } else {                             // vector outputs (gate recomputed)
    int u = t - N_NODES * 64;
    if (u >= N_NODES * 32) return;
    int n = u >> 5, d = u & 31;
    const float* s = nf + (long)n * 160;
    float a = attr[n];
    float gacc = 0.f;
    #pragma unroll 8
    for (int k = 0; k < 64; ++k) gacc = fmaf(s[k], sc_ws[k * 96 + 64 + d], gacc);
    float gpre = (agg[(long)n * 192 + 64 + d] + gacc * C_INV8) * a;
    float g = 1.f / (1.f + __expf(-gpre));
    const float* v = s + 64;
    float s0 = 0.f, s1 = 0.f, s2 = 0.f;
    #pragma unroll 8
    for (int cc = 0; cc < 32; ++cc) {
      float wv = sc_wv[cc * 32 + d];
      s0 = fmaf(v[3 * cc + 0], wv, s0);
      s1 = fmaf(v[3 * cc + 1], wv, s1);
      s2 = fmaf(v[3 * cc + 2], wv, s2);
    }
    const float* ag = agg + (long)n * 192 + 96;
    float p0 = (ag[d]      + s0 * C_INV_S32) * a;
    float p1 = (ag[32 + d] + s1 * C_INV_S32) * a;
    float p2 = (ag[64 + d] + s2 * C_INV_S32) * a;
    float* o = out + (long)n * 160 + 64 + 3 * d;
    o[0] = g * p0; o[1] = g * p1; o[2] = g * p2;
  }
}

extern "C" void kernel_launch(void* const* d_in, const int* in_sizes, int n_in,
                              void* d_out, int out_size, void* d_ws, size_t ws_size,
                              hipStream_t stream)
{
  const float* nf      = (const float*)d_in[0];
  const float* attr    = (const float*)d_in[1];
  const int*   esrc    = (const int*)d_in[2];
  const int*   edst    = (const int*)d_in[3];
  const float* eattr   = (const float*)d_in[4];
  const float* escal   = (const float*)d_in[5];
  const float* lin1_ws = (const float*)d_in[6];
  const float* lin1_wv = (const float*)d_in[7];
  const float* fc_w1   = (const float*)d_in[8];
  const float* fc_w2   = (const float*)d_in[9];
  const float* sc_ws   = (const float*)d_in[10];
  const float* sc_wv   = (const float*)d_in[11];
  const float* lin2_ws = (const float*)d_in[12];
  const float* lin2_wv = (const float*)d_in[13];
  float* out = (float*)d_out;

  char* base = (char*)d_ws;
  size_t off = 0;
  auto carve = [&](size_t bytes) { void* p = base + off; off = (off + bytes + 63) & ~(size_t)63; return p; };
  float* h_s   = (float*)carve((size_t)N_NODES * 64 * 4);
  float* h_v   = (float*)carve((size_t)N_NODES * 96 * 4);
  float* agg   = (float*)carve((size_t)N_NODES * 192 * 4);
  unsigned short* w1t = (unsigned short*)carve(4096 * 2);
  unsigned short* w2t = (unsigned short*)carve(14336 * 2);
  unsigned short* wst = (unsigned short*)carve(9216 * 2);
  unsigned short* wvt = (unsigned short*)carve(4096 * 2);
  int* deg    = (int*)carve((size_t)N_NODES * 4);
  int* startp = (int*)carve((size_t)(N_NODES + 1) * 4);
  int* cursor = (int*)carve((size_t)N_NODES * 4);
  int* pos    = (int*)carve((size_t)N_EDGES * 4);
  unsigned short* e_out = (unsigned short*)carve((size_t)N_EDGES * 192 * 2);

  k_prep<<<124, 256, 0, stream>>>(fc_w1, fc_w2, lin2_ws, lin2_wv, w1t, w2t, wst, wvt);
  k_node<<<(N_NODES * 96 + 255) / 256, 256, 0, stream>>>(nf, attr, lin1_ws, lin1_wv, h_s, h_v);

  hipMemsetAsync(deg, 0, (size_t)N_NODES * 4, stream);
  k_deg<<<(N_EDGES + 255) / 256, 256, 0, stream>>>(edst, deg);
  k_scan<<<1, 1024, 0, stream>>>(deg, startp, cursor);
  k_fill<<<(N_EDGES + 255) / 256, 256, 0, stream>>>(edst, cursor, pos);
  k_edge2<<<N_EDGES / 64, 256, 0, stream>>>(escal, eattr, esrc, pos,
                                            w1t, w2t, wst, wvt, h_s, h_v, e_out);
  k_agg<<<(N_NODES * 96 + 255) / 256, 256, 0, stream>>>(startp, e_out, agg);
  k_fin<<<(N_NODES * 96 + 255) / 256, 256, 0, stream>>>(nf, attr, agg, sc_ws, sc_wv, out);
}

// Round 9
// 698.948 us; speedup vs baseline: 1.3311x; 1.2741x over previous
//
#include <hip/hip_runtime.h>

constexpr int N_NODES = 40000;
constexpr int N_EDGES = 640000;

constexpr float C_INV8     = 0.125f;                  // 1/sqrt(64)
constexpr float C_INV_S32  = 0.17677669529663687f;    // 1/sqrt(32)
constexpr float C_INV_S3   = 0.57735026918962576f;    // 1/sqrt(3)
constexpr float C_INV_S2   = 0.70710678118654752f;    // 1/sqrt(2)
constexpr float C_INV_S96  = 0.10206207261596575f;    // 1/sqrt(96)
constexpr float C_INV_S128 = 0.08838834764831845f;    // 1/sqrt(128)
constexpr float C_INV_NN   = 0.25f;                   // 1/sqrt(16)

typedef __attribute__((ext_vector_type(8))) short short8;
typedef __attribute__((ext_vector_type(4))) float f32x4;

__device__ __forceinline__ unsigned short f2bf(float x) {
  __bf16 b = (__bf16)x;                      // hw v_cvt (RNE)
  return __builtin_bit_cast(unsigned short, b);
}
__device__ __forceinline__ float bf2f(unsigned short h) {
  return __uint_as_float(((unsigned int)h) << 16);
}

// ---- prep: bf16-transpose weights to [col][k]; fold agg scales into lin2 ----
__global__ __launch_bounds__(256) void k_prep(
    const float* __restrict__ fc_w1, const float* __restrict__ fc_w2,
    const float* __restrict__ lin2_ws, const float* __restrict__ lin2_wv,
    unsigned short* __restrict__ w1t, unsigned short* __restrict__ w2t,
    unsigned short* __restrict__ wst, unsigned short* __restrict__ wvt)
{
  int t = blockIdx.x * 256 + threadIdx.x;
  if (t < 4096) {                       // w1t: 64x64
    int c = t >> 6, k = t & 63;
    w1t[c * 64 + k] = f2bf(fc_w1[k * 64 + c]);
  } else if (t < 4096 + 14336) {        // w2t: 224x64
    int u = t - 4096; int c = u >> 6, k = u & 63;
    w2t[c * 64 + k] = f2bf(fc_w2[k * 224 + c]);
  } else if (t < 18432 + 9216) {        // wst: 96x96 (pre-scaled)
    int u = t - 18432; int c = u / 96, k = u - c * 96;
    wst[c * 96 + k] = f2bf(lin2_ws[k * 96 + c] * (C_INV_NN * C_INV_S96));
  } else if (t < 27648 + 4096) {        // wvt: 32x128 (pre-scaled)
    int u = t - 27648; int d = u >> 7, k = u & 127;
    wvt[d * 128 + k] = f2bf(lin2_wv[k * 32 + d] * (C_INV_NN * C_INV_S128));
  }
}

// ---------------- K1: fused h_s / h_v ----------------
__global__ __launch_bounds__(256) void k_node(
    const float* __restrict__ nf, const float* __restrict__ attr,
    const float* __restrict__ ws_, const float* __restrict__ wv_,
    float* __restrict__ h_s, float* __restrict__ h_v)
{
  int t = blockIdx.x * 256 + threadIdx.x;
  if (t < N_NODES * 64) {
    int n = t >> 6, c = t & 63;
    const float* s = nf + (long)n * 160;
    float acc = 0.f;
    #pragma unroll 8
    for (int k = 0; k < 64; ++k) acc = fmaf(s[k], ws_[k * 64 + c], acc);
    h_s[t] = acc * attr[n] * C_INV8;
  } else {
    int u = t - N_NODES * 64;
    if (u >= N_NODES * 32) return;
    int n = u >> 5, d = u & 31;
    const float* v = nf + (long)n * 160 + 64;
    float a0 = 0.f, a1 = 0.f, a2 = 0.f;
    #pragma unroll 8
    for (int c = 0; c < 32; ++c) {
      float wv = wv_[c * 32 + d];
      a0 = fmaf(v[3 * c + 0], wv, a0);
      a1 = fmaf(v[3 * c + 1], wv, a1);
      a2 = fmaf(v[3 * c + 2], wv, a2);
    }
    float sc = attr[n] * C_INV_S32;
    h_v[(long)u * 3 + 0] = a0 * sc;
    h_v[(long)u * 3 + 1] = a1 * sc;
    h_v[(long)u * 3 + 2] = a2 * sc;
  }
}

// ---------------- CSR build ----------------
__global__ __launch_bounds__(256) void k_deg(const int* __restrict__ edst,
                                             int* __restrict__ deg)
{
  int e = blockIdx.x * 256 + threadIdx.x;
  if (e < N_EDGES) atomicAdd(&deg[edst[e]], 1);
}

__global__ __launch_bounds__(1024) void k_scan(const int* __restrict__ deg,
                                               int* __restrict__ start,
                                               int* __restrict__ cursor)
{
  __shared__ int psum[1024];
  int tid = threadIdx.x;
  const int PER = 40;
  int base = tid * PER;
  int s = 0;
  for (int i = 0; i < PER; ++i) {
    int idx = base + i;
    if (idx < N_NODES) s += deg[idx];
  }
  psum[tid] = s;
  __syncthreads();
  for (int off = 1; off < 1024; off <<= 1) {
    int v = psum[tid];
    int u = (tid >= off) ? psum[tid - off] : 0;
    __syncthreads();
    psum[tid] = v + u;
    __syncthreads();
  }
  int run = (tid == 0) ? 0 : psum[tid - 1];
  for (int i = 0; i < PER; ++i) {
    int idx = base + i;
    if (idx < N_NODES) {
      start[idx] = run; cursor[idx] = run;
      run += deg[idx];
    }
  }
  if (tid == 1023) start[N_NODES] = run;
}

// pos[e] = sorted slot of edge e (inverse permutation)
__global__ __launch_bounds__(256) void k_fill(const int* __restrict__ edst,
                                              int* __restrict__ cursor,
                                              int* __restrict__ pos)
{
  int e = blockIdx.x * 256 + threadIdx.x;
  if (e < N_EDGES) {
    int p = atomicAdd(&cursor[edst[e]], 1);
    pos[e] = p;
  }
}

// ---- K2: fused FC(MFMA) + messages + per-edge lin2(MFMA) -> scatter e_out ----
// Edges in ORIGINAL order (sequential reads); rows scatter-stored to sorted
// slots pos[e]. block = 4 waves x 16 edges; LDS warp-private, 0 barriers.
// launch_bounds (256,3): VGPR cap ~170 -- (256,5) forced spill-to-scratch (R8).
__global__ __launch_bounds__(256, 3) void k_edge2(
    const float* __restrict__ escal, const float* __restrict__ eattr,
    const int* __restrict__ esrc, const int* __restrict__ pos,
    const unsigned short* __restrict__ w1t, const unsigned short* __restrict__ w2t,
    const unsigned short* __restrict__ wst, const unsigned short* __restrict__ wvt,
    const float* __restrict__ h_s, const float* __restrict__ h_v,
    unsigned short* __restrict__ e_out)
{
  __shared__ unsigned short w_lds[64 * 232];    // 29.7 KB (hid + w + o reuse)
  int tid = threadIdx.x, warp = tid >> 6, lane = tid & 63;
  int lr = lane & 15, lg = lane >> 4;
  long e0 = (long)blockIdx.x * 64;
  int r0 = warp * 16;
  unsigned short* wp = w_lds + r0 * 232;        // warp-private slice

  // ---- per-lane edge ingredients (sequential edge id) ----
  long eM = e0 + r0 + lr;
  int srcM = esrc[eM];
  float4 ea4 = *reinterpret_cast<const float4*>(eattr + eM * 4);
  float ea0 = ea4.x, e1x = ea4.y, e1y = ea4.z, e1z = ea4.w;
  float esv[16];
  {
    const float* hsr = h_s + (long)srcM * 64;
    *reinterpret_cast<float4*>(&esv[0])  = *reinterpret_cast<const float4*>(hsr + lg * 8);
    *reinterpret_cast<float4*>(&esv[4])  = *reinterpret_cast<const float4*>(hsr + lg * 8 + 4);
    *reinterpret_cast<float4*>(&esv[8])  = *reinterpret_cast<const float4*>(hsr + 32 + lg * 8);
    *reinterpret_cast<float4*>(&esv[12]) = *reinterpret_cast<const float4*>(hsr + 32 + lg * 8 + 4);
  }
  float evv[24];
  {
    const float* hvr = h_v + (long)srcM * 96 + lg * 24;
    #pragma unroll
    for (int q = 0; q < 6; ++q)
      *reinterpret_cast<float4*>(&evv[4 * q]) = *reinterpret_cast<const float4*>(hvr + 4 * q);
  }

  // ---- layer1: hid = silu((escal @ W1)/8); sequential A rows ----
  f32x4 acc[4] = {};
  #pragma unroll
  for (int ks = 0; ks < 2; ++ks) {
    const float* ap = escal + eM * 64 + ks * 32 + lg * 8;
    float4 a01 = *reinterpret_cast<const float4*>(ap);
    float4 a23 = *reinterpret_cast<const float4*>(ap + 4);
    short8 af;
    af[0] = (short)f2bf(a01.x); af[1] = (short)f2bf(a01.y);
    af[2] = (short)f2bf(a01.z); af[3] = (short)f2bf(a01.w);
    af[4] = (short)f2bf(a23.x); af[5] = (short)f2bf(a23.y);
    af[6] = (short)f2bf(a23.z); af[7] = (short)f2bf(a23.w);
    #pragma unroll
    for (int nt = 0; nt < 4; ++nt) {
      short8 bf = *reinterpret_cast<const short8*>(w1t + (nt * 16 + lr) * 64 + ks * 32 + lg * 8);
      acc[nt] = __builtin_amdgcn_mfma_f32_16x16x32_bf16(af, bf, acc[nt], 0, 0, 0);
    }
  }
  #pragma unroll
  for (int nt = 0; nt < 4; ++nt)
    #pragma unroll
    for (int r = 0; r < 4; ++r) {
      float x = acc[nt][r] * C_INV8;
      float h = x / (1.f + __expf(-x));
      wp[(lg * 4 + r) * 72 + nt * 16 + lr] = f2bf(h);
    }

  // ---- layer2: w = (hid @ W2)/8 ----
  f32x4 acc2[14] = {};
  #pragma unroll
  for (int ks = 0; ks < 2; ++ks) {
    short8 af = *reinterpret_cast<const short8*>(wp + lr * 72 + ks * 32 + lg * 8);
    #pragma unroll
    for (int nt = 0; nt < 14; ++nt) {
      short8 bf = *reinterpret_cast<const short8*>(w2t + (nt * 16 + lr) * 64 + ks * 32 + lg * 8);
      acc2[nt] = __builtin_amdgcn_mfma_f32_16x16x32_bf16(af, bf, acc2[nt], 0, 0, 0);
    }
  }
  #pragma unroll
  for (int nt = 0; nt < 14; ++nt)
    #pragma unroll
    for (int r = 0; r < 4; ++r)
      wp[(lg * 4 + r) * 232 + nt * 16 + lr] = f2bf(acc2[nt][r] * C_INV8);

  const unsigned short* wrow = wp + lr * 232;
  short8 w1a = *reinterpret_cast<const short8*>(wrow + lg * 8);
  short8 w1b = *reinterpret_cast<const short8*>(wrow + 32 + lg * 8);
  short8 w2a = *reinterpret_cast<const short8*>(wrow + 64 + lg * 8);
  short8 w2b = *reinterpret_cast<const short8*>(wrow + 96 + lg * 8);
  short8 w3s = *reinterpret_cast<const short8*>(wrow + 128 + lg * 8);
  short8 w4s = *reinterpret_cast<const short8*>(wrow + 160 + lg * 8);
  short8 w5s = *reinterpret_cast<const short8*>(wrow + 192 + lg * 8);

  // ---- S-GEMM: [16 edges x 96 mid_s] @ wst -> 16x96 (scaled) ----
  f32x4 accS[6] = {};
  {
    short8 aS;
    #pragma unroll
    for (int j = 0; j < 8; ++j) aS[j] = (short)f2bf(bf2f((unsigned short)w1a[j]) * esv[j] * ea0);
    #pragma unroll
    for (int nt = 0; nt < 6; ++nt) {
      short8 b = *reinterpret_cast<const short8*>(wst + (nt * 16 + lr) * 96 + lg * 8);
      accS[nt] = __builtin_amdgcn_mfma_f32_16x16x32_bf16(aS, b, accS[nt], 0, 0, 0);
    }
    #pragma unroll
    for (int j = 0; j < 8; ++j) aS[j] = (short)f2bf(bf2f((unsigned short)w1b[j]) * esv[8 + j] * ea0);
    #pragma unroll
    for (int nt = 0; nt < 6; ++nt) {
      short8 b = *reinterpret_cast<const short8*>(wst + (nt * 16 + lr) * 96 + 32 + lg * 8);
      accS[nt] = __builtin_amdgcn_mfma_f32_16x16x32_bf16(aS, b, accS[nt], 0, 0, 0);
    }
    #pragma unroll
    for (int j = 0; j < 8; ++j) {
      float dot = evv[3 * j] * e1x + evv[3 * j + 1] * e1y + evv[3 * j + 2] * e1z;
      aS[j] = (short)f2bf(bf2f((unsigned short)w4s[j]) * dot * C_INV_S3);
    }
    #pragma unroll
    for (int nt = 0; nt < 6; ++nt) {
      short8 b = *reinterpret_cast<const short8*>(wst + (nt * 16 + lr) * 96 + 64 + lg * 8);
      accS[nt] = __builtin_amdgcn_mfma_f32_16x16x32_bf16(aS, b, accS[nt], 0, 0, 0);
    }
  }

  // ---- V-GEMMs: per comp i, [16 x 128 mid_v_i] @ wvt -> 16x32 (scaled) ----
  f32x4 accV[6] = {};
  #pragma unroll
  for (int i = 0; i < 3; ++i) {
    float e1i = (i == 0) ? e1x : (i == 1) ? e1y : e1z;
    short8 aV;
    #pragma unroll
    for (int j = 0; j < 8; ++j) aV[j] = (short)f2bf(bf2f((unsigned short)w2a[j]) * esv[j] * e1i);
    #pragma unroll
    for (int nt = 0; nt < 2; ++nt) {
      short8 b = *reinterpret_cast<const short8*>(wvt + (nt * 16 + lr) * 128 + lg * 8);
      accV[i * 2 + nt] = __builtin_amdgcn_mfma_f32_16x16x32_bf16(aV, b, accV[i * 2 + nt], 0, 0, 0);
    }
    #pragma unroll
    for (int j = 0; j < 8; ++j) aV[j] = (short)f2bf(bf2f((unsigned short)w2b[j]) * esv[8 + j] * e1i);
    #pragma unroll
    for (int nt = 0; nt < 2; ++nt) {
      short8 b = *reinterpret_cast<const short8*>(wvt + (nt * 16 + lr) * 128 + 32 + lg * 8);
      accV[i * 2 + nt] = __builtin_amdgcn_mfma_f32_16x16x32_bf16(aV, b, accV[i * 2 + nt], 0, 0, 0);
    }
    #pragma unroll
    for (int j = 0; j < 8; ++j) aV[j] = (short)f2bf(bf2f((unsigned short)w3s[j]) * evv[3 * j + i] * ea0);
    #pragma unroll
    for (int nt = 0; nt < 2; ++nt) {
      short8 b = *reinterpret_cast<const short8*>(wvt + (nt * 16 + lr) * 128 + 64 + lg * 8);
      accV[i * 2 + nt] = __builtin_amdgcn_mfma_f32_16x16x32_bf16(aV, b, accV[i * 2 + nt], 0, 0, 0);
    }
    #pragma unroll
    for (int j = 0; j < 8; ++j) {
      float ex = evv[3 * j], ey = evv[3 * j + 1], ez = evv[3 * j + 2];
      float cr = (i == 0) ? (ey * e1z - ez * e1y)
               : (i == 1) ? (ez * e1x - ex * e1z)
                          : (ex * e1y - ey * e1x);
      aV[j] = (short)f2bf(bf2f((unsigned short)w5s[j]) * cr * C_INV_S2);
    }
    #pragma unroll
    for (int nt = 0; nt < 2; ++nt) {
      short8 b = *reinterpret_cast<const short8*>(wvt + (nt * 16 + lr) * 128 + 96 + lg * 8);
      accV[i * 2 + nt] = __builtin_amdgcn_mfma_f32_16x16x32_bf16(aV, b, accV[i * 2 + nt], 0, 0, 0);
    }
  }

  // ---- stage o (192 bf16/edge) into own warp slice (stride 232) ----
  #pragma unroll
  for (int nt = 0; nt < 6; ++nt)
    #pragma unroll
    for (int r = 0; r < 4; ++r)
      wp[(lg * 4 + r) * 232 + nt * 16 + lr] = f2bf(accS[nt][r]);
  #pragma unroll
  for (int q = 0; q < 6; ++q) {
    int i = q >> 1, nt = q & 1;
    #pragma unroll
    for (int r = 0; r < 4; ++r)
      wp[(lg * 4 + r) * 232 + 96 + i * 32 + nt * 16 + lr] = f2bf(accV[q][r]);
  }

  // ---- scatter-store: row -> sorted slot pos[e] ----
  #pragma unroll
  for (int c3 = 0; c3 < 6; ++c3) {
    int chunk = c3 * 64 + lane;           // 0..383
    int row = chunk / 24, col = chunk % 24;
    int p = pos[e0 + r0 + row];           // L1-hit after first touch
    float4 v4 = *reinterpret_cast<const float4*>(wp + row * 232 + col * 8);
    *reinterpret_cast<float4*>(e_out + (long)p * 192 + col * 8) = v4;
  }
}

// ---- K_agg: sequential streaming reduce (e_out is dst-sorted) ----
__global__ __launch_bounds__(256) void k_agg(
    const int* __restrict__ start, const unsigned short* __restrict__ eo,
    float* __restrict__ agg)
{
  int t = blockIdx.x * 256 + threadIdx.x;
  if (t >= N_NODES * 96) return;
  int n = t / 96, c = t - n * 96;
  int s0 = start[n], s1 = start[n + 1];
  const unsigned int* base = reinterpret_cast<const unsigned int*>(eo);
  float a0 = 0.f, a1 = 0.f;
  long idx = (long)s0 * 96 + c;
  int k = s0;
  for (; k + 8 <= s1; k += 8) {
    unsigned int v[8];
    #pragma unroll
    for (int j = 0; j < 8; ++j) v[j] = base[idx + (long)j * 96];
    #pragma unroll
    for (int j = 0; j < 8; ++j) {
      a0 += bf2f((unsigned short)(v[j] & 0xffffu));
      a1 += bf2f((unsigned short)(v[j] >> 16));
    }
    idx += 8 * 96;
  }
  for (; k < s1; ++k) {
    unsigned int v = base[idx];
    a0 += bf2f((unsigned short)(v & 0xffffu));
    a1 += bf2f((unsigned short)(v >> 16));
    idx += 96;
  }
  agg[(long)n * 192 + 2 * c]     = a0;
  agg[(long)n * 192 + 2 * c + 1] = a1;
}

// ---------------- K3: fused output head ----------------
__global__ __launch_bounds__(256) void k_fin(
    const float* __restrict__ nf, const float* __restrict__ attr,
    const float* __restrict__ agg, const float* __restrict__ sc_ws,
    const float* __restrict__ sc_wv, float* __restrict__ out)
{
  int t = blockIdx.x * 256 + threadIdx.x;
  if (t < N_NODES * 64) {              // scalar outputs
    int n = t >> 6, cch = t & 63;
    const float* s = nf + (long)n * 160;
    float acc2 = 0.f;
    #pragma unroll 8
    for (int k = 0; k < 64; ++k) acc2 = fmaf(s[k], sc_ws[k * 96 + cch], acc2);
    float pre = (agg[(long)n * 192 + cch] + acc2 * C_INV8) * attr[n];
    out[(long)n * 160 + cch] = pre / (1.f + __expf(-pre));
  } else {                             // vector outputs (gate recomputed)
    int u = t - N_NODES * 64;
    if (u >= N_NODES * 32) return;
    int n = u >> 5, d = u & 31;
    const float* s = nf + (long)n * 160;
    float a = attr[n];
    float gacc = 0.f;
    #pragma unroll 8
    for (int k = 0; k < 64; ++k) gacc = fmaf(s[k], sc_ws[k * 96 + 64 + d], gacc);
    float gpre = (agg[(long)n * 192 + 64 + d] + gacc * C_INV8) * a;
    float g = 1.f / (1.f + __expf(-gpre));
    const float* v = s + 64;
    float s0 = 0.f, s1 = 0.f, s2 = 0.f;
    #pragma unroll 8
    for (int cc = 0; cc < 32; ++cc) {
      float wv = sc_wv[cc * 32 + d];
      s0 = fmaf(v[3 * cc + 0], wv, s0);
      s1 = fmaf(v[3 * cc + 1], wv, s1);
      s2 = fmaf(v[3 * cc + 2], wv, s2);
    }
    const float* ag = agg + (long)n * 192 + 96;
    float p0 = (ag[d]      + s0 * C_INV_S32) * a;
    float p1 = (ag[32 + d] + s1 * C_INV_S32) * a;
    float p2 = (ag[64 + d] + s2 * C_INV_S32) * a;
    float* o = out + (long)n * 160 + 64 + 3 * d;
    o[0] = g * p0; o[1] = g * p1; o[2] = g * p2;
  }
}

extern "C" void kernel_launch(void* const* d_in, const int* in_sizes, int n_in,
                              void* d_out, int out_size, void* d_ws, size_t ws_size,
                              hipStream_t stream)
{
  const float* nf      = (const float*)d_in[0];
  const float* attr    = (const float*)d_in[1];
  const int*   esrc    = (const int*)d_in[2];
  const int*   edst    = (const int*)d_in[3];
  const float* eattr   = (const float*)d_in[4];
  const float* escal   = (const float*)d_in[5];
  const float* lin1_ws = (const float*)d_in[6];
  const float* lin1_wv = (const float*)d_in[7];
  const float* fc_w1   = (const float*)d_in[8];
  const float* fc_w2   = (const float*)d_in[9];
  const float* sc_ws   = (const float*)d_in[10];
  const float* sc_wv   = (const float*)d_in[11];
  const float* lin2_ws = (const float*)d_in[12];
  const float* lin2_wv = (const float*)d_in[13];
  float* out = (float*)d_out;

  char* base = (char*)d_ws;
  size_t off = 0;
  auto carve = [&](size_t bytes) { void* p = base + off; off = (off + bytes + 63) & ~(size_t)63; return p; };
  float* h_s   = (float*)carve((size_t)N_NODES * 64 * 4);
  float* h_v   = (float*)carve((size_t)N_NODES * 96 * 4);
  float* agg   = (float*)carve((size_t)N_NODES * 192 * 4);
  unsigned short* w1t = (unsigned short*)carve(4096 * 2);
  unsigned short* w2t = (unsigned short*)carve(14336 * 2);
  unsigned short* wst = (unsigned short*)carve(9216 * 2);
  unsigned short* wvt = (unsigned short*)carve(4096 * 2);
  int* deg    = (int*)carve((size_t)N_NODES * 4);
  int* startp = (int*)carve((size_t)(N_NODES + 1) * 4);
  int* cursor = (int*)carve((size_t)N_NODES * 4);
  int* pos    = (int*)carve((size_t)N_EDGES * 4);
  unsigned short* e_out = (unsigned short*)carve((size_t)N_EDGES * 192 * 2);

  k_prep<<<124, 256, 0, stream>>>(fc_w1, fc_w2, lin2_ws, lin2_wv, w1t, w2t, wst, wvt);
  k_node<<<(N_NODES * 96 + 255) / 256, 256, 0, stream>>>(nf, attr, lin1_ws, lin1_wv, h_s, h_v);

  hipMemsetAsync(deg, 0, (size_t)N_NODES * 4, stream);
  k_deg<<<(N_EDGES + 255) / 256, 256, 0, stream>>>(edst, deg);
  k_scan<<<1, 1024, 0, stream>>>(deg, startp, cursor);
  k_fill<<<(N_EDGES + 255) / 256, 256, 0, stream>>>(edst, cursor, pos);
  k_edge2<<<N_EDGES / 64, 256, 0, stream>>>(escal, eattr, esrc, pos,
                                            w1t, w2t, wst, wvt, h_s, h_v, e_out);
  k_agg<<<(N_NODES * 96 + 255) / 256, 256, 0, stream>>>(startp, e_out, agg);
  k_fin<<<(N_NODES * 96 + 255) / 256, 256, 0, stream>>>(nf, attr, agg, sc_ws, sc_wv, out);
}